// Round 1
// baseline (123.195 us; speedup 1.0000x reference)
//
#include <hip/hip_runtime.h>
#include <hip/hip_bf16.h>

// Problem: B=8, N=4096, H=256, F=6
//   Wt[b][n][h] = sum_f osc[f][h][n] * sin(freq_f * t[b] + phase[f][n])
//   out[b][m][n] = sum_h x[b][m][h] * Wt[b][n][h]
//
// R9: FUSED single kernel, ZERO workspace use.
//   Evidence: top-5 rocprof dispatches are all 43 µs fillBufferAligned
//   writing 256 MiB = the harness's d_ws re-poison, inside the timed
//   region (43 + ~8 build_w + ~35 gemm + overhead = 94 µs measured).
//   Avoiding d_ws removes that fixed 43 µs.
//   Structure: 256 blocks (1/CU), 512 thr. Each block:
//     - prefetches its FULL X tile (depth-4, 64 floats/thread) to regs
//     - builds the whole Wt[b] (256n x 256h bf16, 135 KB) in LDS from
//       osc (L2-broadcast) + per-block sin table (proven build_w
//       transpose scheme, ping-pong tr buffers, lgk-only barriers)
//     - GEMM BM=128 x BN=256 with B fully LDS-resident; A-only staging.
//   Numerics bit-identical to R8 (same op order everywhere).

#define B_  8
#define N_  4096
#define H_  256

typedef __attribute__((ext_vector_type(8))) short s8v;   // 8 bf16 (A/B frag)
typedef __attribute__((ext_vector_type(4))) float f4v;   // C/D frag

// LDS-only barrier: no vmcnt drain (global prefetch stays in flight).
#define LGK_BARRIER() asm volatile("s_waitcnt lgkmcnt(0)\n\ts_barrier" ::: "memory")

#define LDW 264   // Wt row stride in shorts (256+8 pad; 528 B -> 2-way banks, free)
#define LDA 72    // As row stride in shorts (144 B, aliasing class measured clean R6)

__device__ __constant__ float c_freqs[6] = {1.f, 2.f, 4.f, 8.f, 7.f, 5.f};

__global__ __launch_bounds__(512, 2) void fused(
    const float* __restrict__ X,       // [8][4096][256] fp32
    const float* __restrict__ t,       // [8][1]
    const float* __restrict__ osc,     // [6][256][256]  osc[f][h][n]
    const float* __restrict__ phase,   // [6][256]       phase[f][n]
    float* __restrict__ out)           // [8][4096][256] fp32
{
    __shared__ short Wt[256 * LDW];    // 135.2 KB  Wt[n][h] bf16, full K resident
    __shared__ union {
        struct {
            float s[6 * 256];          // 6 KB    sin table s[f][n]
            float tr[2][2][16 * 68];   // 17.4 KB transpose staging (group, ping-pong)
        } bld;
        short As[128 * LDA];           // 18.4 KB A staging (gemm phase only)
    } u;                               // total LDS = 158.7 KB <= 160 KB

    const int b     = blockIdx.y;
    const int mTile = blockIdx.x;      // 0..31, BM=128
    const int tid   = threadIdx.x;

    const float* Xb = X   + (size_t)b * N_ * H_ + (size_t)mTile * 128 * H_;
    float* Ob       = out + (size_t)b * N_ * H_ + (size_t)mTile * 128 * H_;

    // ---- depth-4 X prefetch: whole 128x256 fp32 tile -> regs (64 VGPR).
    //      Completes during the ~12 us L2-bound build phase (HBM idle then).
    const int arow = tid >> 2;             // 0..127
    const int aseg = (tid & 3) * 16;       // 0,16,32,48
    const float* pa = Xb + (size_t)arow * H_ + aseg;
    float4 av[4][4];
#pragma unroll
    for (int sl = 0; sl < 4; ++sl)
#pragma unroll
        for (int j = 0; j < 4; ++j)
            av[sl][j] = *(const float4*)(pa + sl * 64 + j * 4);

    // ---- phase 1: per-block sin table (3 sinf/thread) ----
    const float tb = t[b];
#pragma unroll
    for (int k = 0; k < 3; ++k) {
        int idx = tid + k * 512;           // idx = f*256 + n
        u.bld.s[idx] = __sinf(c_freqs[idx >> 8] * tb + phase[idx]);
    }
    LGK_BARRIER();

    // ---- phase 2: build Wt[n][h] in LDS; 32 passes x 2 groups = 64 subtiles
    //      of 16h x 64n (build_w's proven transpose scheme, in-LDS dest).
    const int g  = tid >> 8;               // 256-thread group 0/1
    const int tt = tid & 255;
    const int nr = (tt & 15) * 4;
    const int hr = tt >> 4;                // 0..15
    const int nw = tt >> 2;                // 0..63
    const int hw = (tt & 3) * 4;           // 0,4,8,12
    for (int p = 0; p < 32; ++p) {
        const int s  = p * 2 + g;          // 0..63
        const int h0 = (s & 15) * 16;
        const int n0 = (s >> 4) * 64;
        float4 acc = make_float4(0.f, 0.f, 0.f, 0.f);
#pragma unroll
        for (int f = 0; f < 6; ++f) {
            float4 sv = *(const float4*)&u.bld.s[f * 256 + n0 + nr];
            float4 o  = *(const float4*)&osc[f * 65536 + (h0 + hr) * 256 + n0 + nr];
            acc.x += o.x * sv.x;  acc.y += o.y * sv.y;
            acc.z += o.z * sv.z;  acc.w += o.w * sv.w;
        }
        *(float4*)&u.bld.tr[g][p & 1][hr * 68 + nr] = acc;
        LGK_BARRIER();                     // ping-pong: 1 barrier/pass is race-free
        float v0 = u.bld.tr[g][p & 1][(hw + 0) * 68 + nw];
        float v1 = u.bld.tr[g][p & 1][(hw + 1) * 68 + nw];
        float v2 = u.bld.tr[g][p & 1][(hw + 2) * 68 + nw];
        float v3 = u.bld.tr[g][p & 1][(hw + 3) * 68 + nw];
        union { __hip_bfloat162 h2[2]; unsigned long long q; } cv;
        cv.h2[0] = __float22bfloat162_rn(make_float2(v0, v1));
        cv.h2[1] = __float22bfloat162_rn(make_float2(v2, v3));
        *(unsigned long long*)&Wt[(n0 + nw) * LDW + h0 + hw] = cv.q;
    }
    LGK_BARRIER();                         // Wt complete; union switches bld -> As

    // ---- phase 3: GEMM. B resident in Wt LDS; stage A only, BK=64 x 4.
    const int lane   = tid & 63;
    const int wave   = tid >> 6;           // 0..7
    const int lane15 = lane & 15;
    const int quad   = lane >> 4;          // 0..3
    const int wm     = wave >> 2;          // 0..1: 64-row band
    const int wn     = wave & 3;           // 0..3: 64-col band

    f4v acc[4][4] = {};

#pragma unroll
    for (int it = 0; it < 4; ++it) {
        // stage A iter it from prefetched regs (fp32 -> bf16 in-register)
        union { __hip_bfloat162 h2[4]; uint4 q; } c0, c1;
        c0.h2[0] = __float22bfloat162_rn(make_float2(av[it][0].x, av[it][0].y));
        c0.h2[1] = __float22bfloat162_rn(make_float2(av[it][0].z, av[it][0].w));
        c0.h2[2] = __float22bfloat162_rn(make_float2(av[it][1].x, av[it][1].y));
        c0.h2[3] = __float22bfloat162_rn(make_float2(av[it][1].z, av[it][1].w));
        c1.h2[0] = __float22bfloat162_rn(make_float2(av[it][2].x, av[it][2].y));
        c1.h2[1] = __float22bfloat162_rn(make_float2(av[it][2].z, av[it][2].w));
        c1.h2[2] = __float22bfloat162_rn(make_float2(av[it][3].x, av[it][3].y));
        c1.h2[3] = __float22bfloat162_rn(make_float2(av[it][3].z, av[it][3].w));
        *(uint4*)&u.As[arow * LDA + aseg + 0] = c0.q;
        *(uint4*)&u.As[arow * LDA + aseg + 8] = c1.q;
        LGK_BARRIER();

#pragma unroll
        for (int kh = 0; kh < 2; ++kh) {
            s8v af[4], bf[4];
#pragma unroll
            for (int mt = 0; mt < 4; ++mt)
                af[mt] = *(const s8v*)&u.As[(wm * 64 + mt * 16 + lane15) * LDA + kh * 32 + quad * 8];
#pragma unroll
            for (int nt = 0; nt < 4; ++nt)
                bf[nt] = *(const s8v*)&Wt[(wn * 64 + nt * 16 + lane15) * LDW + it * 64 + kh * 32 + quad * 8];
#pragma unroll
            for (int mt = 0; mt < 4; ++mt)
#pragma unroll
                for (int nt = 0; nt < 4; ++nt)
                    acc[mt][nt] = __builtin_amdgcn_mfma_f32_16x16x32_bf16(
                        af[mt], bf[nt], acc[mt][nt], 0, 0, 0);
        }
        LGK_BARRIER();                     // frag reads retired; next staging may overwrite
    }

    // ---- epilogue: C/D layout col=lane15, row=quad*4+r; nontemporal (write-once)
#pragma unroll
    for (int mt = 0; mt < 4; ++mt) {
#pragma unroll
        for (int r = 0; r < 4; ++r) {
            int row = wm * 64 + mt * 16 + quad * 4 + r;
            float* po = Ob + (size_t)row * H_ + wn * 64 + lane15;
#pragma unroll
            for (int nt = 0; nt < 4; ++nt)
                __builtin_nontemporal_store(acc[mt][nt][r], po + nt * 16);
        }
    }
}

extern "C" void kernel_launch(void* const* d_in, const int* in_sizes, int n_in,
                              void* d_out, int out_size, void* d_ws, size_t ws_size,
                              hipStream_t stream) {
    const float* x     = (const float*)d_in[0];   // [8][4096][256]
    const float* t     = (const float*)d_in[1];   // [8][1]
    const float* osc   = (const float*)d_in[2];   // [6][256][256]
    const float* phase = (const float*)d_in[3];   // [6][256]
    (void)d_ws; (void)ws_size;                    // workspace deliberately UNUSED
    (void)in_sizes; (void)n_in; (void)out_size;

    dim3 gg(32, 8);                               // (mTile, b) = 256 blocks = 1/CU
    fused<<<gg, 512, 0, stream>>>(x, t, osc, phase, (float*)d_out);
}

// Round 2
// 111.195 us; speedup vs baseline: 1.1079x; 1.1079x over previous
//
#include <hip/hip_runtime.h>
#include <hip/hip_bf16.h>

// Problem: B=8, N=4096, H=256, F=6
//   Wt[b][n][h] = sum_f osc[f][h][n] * sin(freq_f * t[b] + phase[f][n])
//   out[b][m][n] = sum_h x[b][m][h] * Wt[b][n][h]
//
// R10 = two-kernel structure (R8) + LDS-FREE streaming gemm.
//   Evidence from R9: the 43 µs / 256 MiB d_ws poison fill is UNCONDITIONAL
//   (R9 used no ws, yet total rose to 123 = fused 58 + fill 43 + out fill
//   + gaps). So ws use is free -> keep build_w -> Wt in ws.
//   R9 also proved fusing the build is a 32x-redundant-work loss.
//   gemm redesign: K=256 fits in 8 k-steps; B panel (128 KB/batch) is
//   L2-resident; A is a single dense stream. So:
//     - NO __shared__, NO barriers at all.
//     - A-frags loaded direct from X (fp32, 2x float4/frag, dense line
//       coverage), converted fp32->bf16 in-register.
//     - B-frags loaded direct from Wt as s8v (16 rows x 64 B segments/instr,
//       L2 hits; row redundancy absorbed by L1/L2).
//     - depth-2 register pipeline over k-steps; 16 waves/CU free-running.

#define B_  8
#define N_  4096
#define H_  256

typedef __attribute__((ext_vector_type(8))) short s8v;   // 8 bf16 (A/B frag)
typedef __attribute__((ext_vector_type(4))) float f4v;   // C/D frag

__global__ __launch_bounds__(256) void build_w(
    const float* __restrict__ osc,     // [6][256][256]  osc[f][h][n]
    const float* __restrict__ t,       // [8][1]
    const float* __restrict__ phase,   // [6][256]       phase[f][n]
    __hip_bfloat16* __restrict__ Wt)   // [8][256][256]  Wt[b][n][h]
{
    const float freqs[6] = {1.f, 2.f, 4.f, 8.f, 7.f, 5.f};
    __shared__ float tr[16 * 68];      // [hlocal][n], stride 68

    const int b  = blockIdx.z;
    const int n0 = blockIdx.y * 64;    // 4 n-tiles
    const int h0 = blockIdx.x * 16;    // 16 h-slices
    const int tid = threadIdx.x;

    const float tb = t[b];
    const int nr = (tid & 15) * 4;
    const int hr = tid >> 4;           // 0..15
    float s[6][4];
#pragma unroll
    for (int f = 0; f < 6; ++f)
#pragma unroll
        for (int j = 0; j < 4; ++j)
            s[f][j] = __sinf(freqs[f] * tb + phase[f * 256 + n0 + nr + j]);

    const int h = h0 + hr;
    float4 acc = make_float4(0.f, 0.f, 0.f, 0.f);
#pragma unroll
    for (int f = 0; f < 6; ++f) {
        float4 o = *(const float4*)&osc[f * 65536 + h * 256 + n0 + nr];
        acc.x += o.x * s[f][0];
        acc.y += o.y * s[f][1];
        acc.z += o.z * s[f][2];
        acc.w += o.w * s[f][3];
    }
    *(float4*)&tr[hr * 68 + nr] = acc;
    __syncthreads();

    const int nw = tid >> 2;           // 0..63
    const int hw = (tid & 3) * 4;      // 0,4,8,12
    float v0 = tr[(hw + 0) * 68 + nw];
    float v1 = tr[(hw + 1) * 68 + nw];
    float v2 = tr[(hw + 2) * 68 + nw];
    float v3 = tr[(hw + 3) * 68 + nw];
    union { __hip_bfloat162 h2[2]; unsigned long long q; } cv;
    cv.h2[0] = __float22bfloat162_rn(make_float2(v0, v1));
    cv.h2[1] = __float22bfloat162_rn(make_float2(v2, v3));
    *(unsigned long long*)(Wt + (size_t)b * 65536 + (size_t)(n0 + nw) * 256 + h0 + hw) = cv.q;
}

// LDS-free streaming GEMM: BM=64, BN=256, K=256 in 8 steps of 32.
// 8 waves: wm in {0,1} (32-row band), wn in {0..3} (64-col band).
__global__ __launch_bounds__(512, 4) void gemm(
    const float* __restrict__ X,              // [8][4096][256] fp32
    const __hip_bfloat16* __restrict__ Wt,    // [8][256][256]  bf16 [b][n][h]
    float* __restrict__ out)                  // [8][4096][256] fp32
{
    const int b     = blockIdx.y;
    const int mTile = blockIdx.x;             // 0..63

    const int tid    = threadIdx.x;
    const int lane   = tid & 63;
    const int wave   = tid >> 6;              // 0..7
    const int lane15 = lane & 15;
    const int quad   = lane >> 4;             // 0..3
    const int wm     = wave >> 2;             // 0..1
    const int wn     = wave & 3;              // 0..3

    const float* Xb          = X   + (size_t)b * N_ * H_ + (size_t)mTile * 64 * H_;
    const __hip_bfloat16* Wb = Wt  + (size_t)b * H_ * H_;
    float* Ob                = out + (size_t)b * N_ * H_ + (size_t)mTile * 64 * H_;

    // per-lane frag base pointers (k-offset quad*8 within each 32-wide step)
    const float* pa[2];
#pragma unroll
    for (int mt = 0; mt < 2; ++mt)
        pa[mt] = Xb + (size_t)(wm * 32 + mt * 16 + lane15) * H_ + quad * 8;
    const __hip_bfloat16* pb[4];
#pragma unroll
    for (int nt = 0; nt < 4; ++nt)
        pb[nt] = Wb + (size_t)(wn * 64 + nt * 16 + lane15) * H_ + quad * 8;

    f4v acc[2][4] = {};

    // depth-2 register pipeline: slot sl holds k-step ks, ks+1
    float4 av[2][2][2];                       // [slot][mt][half]  (8 fp32 = A frag)
    s8v    bv[2][4];                          // [slot][nt]
#pragma unroll
    for (int sl = 0; sl < 2; ++sl) {
        const int k = sl * 32;
#pragma unroll
        for (int mt = 0; mt < 2; ++mt) {
            av[sl][mt][0] = *(const float4*)(pa[mt] + k);
            av[sl][mt][1] = *(const float4*)(pa[mt] + k + 4);
        }
#pragma unroll
        for (int nt = 0; nt < 4; ++nt)
            bv[sl][nt] = *(const s8v*)(pb[nt] + k);
    }

#pragma unroll
    for (int ks = 0; ks < 8; ++ks) {
        const int sl = ks & 1;

        // consume slot sl into locals (so prefetch below may overwrite it)
        s8v af[2], bf[4];
#pragma unroll
        for (int mt = 0; mt < 2; ++mt) {
            union { __hip_bfloat162 h2[4]; s8v v; } cv;
            cv.h2[0] = __float22bfloat162_rn(make_float2(av[sl][mt][0].x, av[sl][mt][0].y));
            cv.h2[1] = __float22bfloat162_rn(make_float2(av[sl][mt][0].z, av[sl][mt][0].w));
            cv.h2[2] = __float22bfloat162_rn(make_float2(av[sl][mt][1].x, av[sl][mt][1].y));
            cv.h2[3] = __float22bfloat162_rn(make_float2(av[sl][mt][1].z, av[sl][mt][1].w));
            af[mt] = cv.v;
        }
#pragma unroll
        for (int nt = 0; nt < 4; ++nt)
            bf[nt] = bv[sl][nt];

        // prefetch k-step ks+2 into slot sl (no barriers anywhere: stays in flight)
        if (ks < 6) {
            const int k = (ks + 2) * 32;
#pragma unroll
            for (int mt = 0; mt < 2; ++mt) {
                av[sl][mt][0] = *(const float4*)(pa[mt] + k);
                av[sl][mt][1] = *(const float4*)(pa[mt] + k + 4);
            }
#pragma unroll
            for (int nt = 0; nt < 4; ++nt)
                bv[sl][nt] = *(const s8v*)(pb[nt] + k);
        }

#pragma unroll
        for (int mt = 0; mt < 2; ++mt)
#pragma unroll
            for (int nt = 0; nt < 4; ++nt)
                acc[mt][nt] = __builtin_amdgcn_mfma_f32_16x16x32_bf16(
                    af[mt], bf[nt], acc[mt][nt], 0, 0, 0);
    }

    // epilogue: C/D layout col=lane15, row=quad*4+r; nontemporal (write-once)
#pragma unroll
    for (int mt = 0; mt < 2; ++mt) {
#pragma unroll
        for (int r = 0; r < 4; ++r) {
            int row = wm * 32 + mt * 16 + quad * 4 + r;
            float* po = Ob + (size_t)row * H_ + wn * 64 + lane15;
#pragma unroll
            for (int nt = 0; nt < 4; ++nt)
                __builtin_nontemporal_store(acc[mt][nt][r], po + nt * 16);
        }
    }
}

extern "C" void kernel_launch(void* const* d_in, const int* in_sizes, int n_in,
                              void* d_out, int out_size, void* d_ws, size_t ws_size,
                              hipStream_t stream) {
    const float* x     = (const float*)d_in[0];   // [8][4096][256]
    const float* t     = (const float*)d_in[1];   // [8][1]
    const float* osc   = (const float*)d_in[2];   // [6][256][256]
    const float* phase = (const float*)d_in[3];   // [6][256]
    __hip_bfloat16* Wt = (__hip_bfloat16*)d_ws;   // ws poison is unconditional -> free to use
    float* out = (float*)d_out;
    (void)in_sizes; (void)n_in; (void)out_size; (void)ws_size;

    dim3 gw(16, 4, 8);                            // (h-slice, n-tile, b) = 512 blocks
    build_w<<<gw, 256, 0, stream>>>(osc, t, phase, Wt);

    dim3 gg(64, 8);                               // (mTile, b) = 512 blocks
    gemm<<<gg, 512, 0, stream>>>(x, Wt, out);
}

// Round 3
// 92.292 us; speedup vs baseline: 1.3348x; 1.2048x over previous
//
#include <hip/hip_runtime.h>
#include <hip/hip_bf16.h>

// Problem: B=8, N=4096, H=256, F=6
//   Wt[b][n][h] = sum_f osc[f][h][n] * sin(freq_f * t[b] + phase[f][n])
//   out[b][m][n] = sum_h x[b][m][h] * Wt[b][n][h]
//
// R11 = R8 two-kernel structure (93.8 known-good) with gemm B-staging
//       rebuilt around global_load_lds:
//   - R9 proved the 43 µs / 256 MiB ws poison is UNCONDITIONAL -> ws free.
//   - R10 proved direct-from-global frag gathers regress (16-way vmem
//     segmentation) -> dense global->LDS staging is mandatory.
//   - B (Wt, already bf16) now staged via global_load_lds width=16:
//     no VGPR round-trip, no ds_write_b128 x4 per thread per iter.
//     Dense 128 B rows would be a 16-way ds_read conflict, so the
//     both-sides XOR swizzle (rule #21): linear LDS dest, global source
//     chunk ^= (row&7), ds_read applies same XOR -> free 2-way.
//   - Bs double-buffered; B(it+1)/A(it+1) issued during phase A; counted
//     s_waitcnt vmcnt(6) before the barrier keeps them in flight across
//     it (T4). Last iter drains with vmcnt(0).
//   - A staging unchanged from R8 (fp32->bf16 must round-trip regs).

#define B_  8
#define N_  4096
#define H_  256

typedef __attribute__((ext_vector_type(8))) short s8v;   // 8 bf16 (A/B frag)
typedef __attribute__((ext_vector_type(4))) float f4v;   // C/D frag

#define AS1 __attribute__((address_space(1)))
#define AS3 __attribute__((address_space(3)))
#define GLOAD_LDS16(g, l) \
    __builtin_amdgcn_global_load_lds((const AS1 void*)(g), (AS3 void*)(l), 16, 0, 0)

__global__ __launch_bounds__(256) void build_w(
    const float* __restrict__ osc,     // [6][256][256]  osc[f][h][n]
    const float* __restrict__ t,       // [8][1]
    const float* __restrict__ phase,   // [6][256]       phase[f][n]
    __hip_bfloat16* __restrict__ Wt)   // [8][256][256]  Wt[b][n][h]
{
    const float freqs[6] = {1.f, 2.f, 4.f, 8.f, 7.f, 5.f};
    __shared__ float tr[16 * 68];      // [hlocal][n], stride 68

    const int b  = blockIdx.z;
    const int n0 = blockIdx.y * 64;    // 4 n-tiles
    const int h0 = blockIdx.x * 16;    // 16 h-slices
    const int tid = threadIdx.x;

    const float tb = t[b];
    const int nr = (tid & 15) * 4;
    const int hr = tid >> 4;           // 0..15
    float s[6][4];
#pragma unroll
    for (int f = 0; f < 6; ++f)
#pragma unroll
        for (int j = 0; j < 4; ++j)
            s[f][j] = __sinf(freqs[f] * tb + phase[f * 256 + n0 + nr + j]);

    const int h = h0 + hr;
    float4 acc = make_float4(0.f, 0.f, 0.f, 0.f);
#pragma unroll
    for (int f = 0; f < 6; ++f) {
        float4 o = *(const float4*)&osc[f * 65536 + h * 256 + n0 + nr];
        acc.x += o.x * s[f][0];
        acc.y += o.y * s[f][1];
        acc.z += o.z * s[f][2];
        acc.w += o.w * s[f][3];
    }
    *(float4*)&tr[hr * 68 + nr] = acc;
    __syncthreads();

    const int nw = tid >> 2;           // 0..63
    const int hw = (tid & 3) * 4;      // 0,4,8,12
    float v0 = tr[(hw + 0) * 68 + nw];
    float v1 = tr[(hw + 1) * 68 + nw];
    float v2 = tr[(hw + 2) * 68 + nw];
    float v3 = tr[(hw + 3) * 68 + nw];
    union { __hip_bfloat162 h2[2]; unsigned long long q; } cv;
    cv.h2[0] = __float22bfloat162_rn(make_float2(v0, v1));
    cv.h2[1] = __float22bfloat162_rn(make_float2(v2, v3));
    *(unsigned long long*)(Wt + (size_t)b * 65536 + (size_t)(n0 + nw) * 256 + h0 + hw) = cv.q;
}

#define LDA 72    // As row stride in shorts (144 B, 2-way class, clean — R6)

// BM=64, BN=256, BK=64 x 4 iters. 8 waves: wm in {0,1}, wn in {0..3}.
__global__ __launch_bounds__(512, 4) void gemm(
    const float* __restrict__ X,              // [8][4096][256] fp32
    const __hip_bfloat16* __restrict__ Wt,    // [8][256][256]  bf16 [b][n][h]
    float* __restrict__ out)                  // [8][4096][256] fp32
{
    __shared__ short As[64 * LDA];            //  9.2 KB, reg-staged (fp32->bf16)
    __shared__ short Bs[2][256 * 64];         // 2x32 KB dense, XOR-swizzled content
                                              // total 73 KB -> 2 blocks/CU

    const int b     = blockIdx.y;
    const int mTile = blockIdx.x;             // 0..63

    const int tid    = threadIdx.x;
    const int lane   = tid & 63;
    const int wave   = tid >> 6;              // 0..7
    const int lane15 = lane & 15;
    const int quad   = lane >> 4;             // 0..3
    const int wm     = wave >> 2;             // 0..1
    const int wn     = wave & 3;              // 0..3

    const float* Xb          = X   + (size_t)b * N_ * H_ + (size_t)mTile * 64 * H_;
    const __hip_bfloat16* Wb = Wt  + (size_t)b * H_ * H_;
    float* Ob                = out + (size_t)b * N_ * H_ + (size_t)mTile * 64 * H_;

    // A staging: 64 rows x 64 k fp32 -> 8 floats/thread (32 B contig)
    const int arow = tid >> 3;                // 0..63
    const int aseg = (tid & 7) * 8;           // 0,8,..,56
    const float* pa = Xb + (size_t)arow * H_ + aseg;

    // B gload_lds: lane covers LDS chunk d = wave*256 + j*64 + lane
    //   -> row n = wave*32 + j*8 + (lane>>3), phys chunk c = lane&7.
    //   Source reads LOGICAL chunk c ^ (n&7)  (n&7 == lane>>3) so that
    //   LDS phys layout ends up row-XOR-swizzled with a LINEAR dest.
    const int brow = lane >> 3;               // 0..7
    const int bchk = (lane & 7) ^ brow;       // logical k-chunk (16 B units)
    const __hip_bfloat16* pbg = Wb + (size_t)(wave * 32 + brow) * H_ + bchk * 8;

    f4v acc[2][4] = {};

    // ---- prologue: B(0) -> Bs[0], A(0) -> regs
#pragma unroll
    for (int j = 0; j < 4; ++j)
        GLOAD_LDS16(pbg + (size_t)j * 8 * H_, &Bs[0][wave * 2048 + j * 512]);
    float4 av[2][2];
    av[0][0] = *(const float4*)(pa + 0);
    av[0][1] = *(const float4*)(pa + 4);

#pragma unroll
    for (int it = 0; it < 4; ++it) {
        const int p = it & 1;
        // stage A(it): fp32 -> bf16 in-register, one ds_write_b128
        union { __hip_bfloat162 h2[4]; uint4 q; } cv;
        cv.h2[0] = __float22bfloat162_rn(make_float2(av[p][0].x, av[p][0].y));
        cv.h2[1] = __float22bfloat162_rn(make_float2(av[p][0].z, av[p][0].w));
        cv.h2[2] = __float22bfloat162_rn(make_float2(av[p][1].x, av[p][1].y));
        cv.h2[3] = __float22bfloat162_rn(make_float2(av[p][1].z, av[p][1].w));
        *(uint4*)&As[arow * LDA + aseg] = cv.q;

        if (it < 3) {
            // issue B(it+1) -> Bs[p^1] and A(it+1) -> regs (stay in flight
            // across the barrier: counted vmcnt, never 0 mid-loop)
#pragma unroll
            for (int j = 0; j < 4; ++j)
                GLOAD_LDS16(pbg + (it + 1) * 64 + (size_t)j * 8 * H_,
                            &Bs[p ^ 1][wave * 2048 + j * 512]);
            av[p ^ 1][0] = *(const float4*)(pa + (it + 1) * 64);
            av[p ^ 1][1] = *(const float4*)(pa + (it + 1) * 64 + 4);
            // newest 6 vmem = B(it+1) x4 + A(it+1) x2 -> vmcnt(6) drains B(it)
            asm volatile("s_waitcnt vmcnt(6) lgkmcnt(0)\n\ts_barrier" ::: "memory");
        } else {
            asm volatile("s_waitcnt vmcnt(0) lgkmcnt(0)\n\ts_barrier" ::: "memory");
        }

        // compute on As + Bs[p]; frag k = kh*32 + quad*8
#pragma unroll
        for (int kh = 0; kh < 2; ++kh) {
            s8v af[2], bf[4];
#pragma unroll
            for (int mt = 0; mt < 2; ++mt)
                af[mt] = *(const s8v*)&As[(wm * 32 + mt * 16 + lane15) * LDA + kh * 32 + quad * 8];
#pragma unroll
            for (int nt = 0; nt < 4; ++nt) {
                const int n  = wn * 64 + nt * 16 + lane15;
                const int pc = ((kh * 4 + quad) ^ (lane15 & 7)) * 8;  // XOR on read
                bf[nt] = *(const s8v*)&Bs[p][n * 64 + pc];
            }
#pragma unroll
            for (int mt = 0; mt < 2; ++mt)
#pragma unroll
                for (int nt = 0; nt < 4; ++nt)
                    acc[mt][nt] = __builtin_amdgcn_mfma_f32_16x16x32_bf16(
                        af[mt], bf[nt], acc[mt][nt], 0, 0, 0);
        }
        if (it < 3)
            asm volatile("s_barrier" ::: "memory");  // reads retired; staging may overwrite
    }

    // epilogue: C/D layout col=lane15, row=quad*4+r; nontemporal (write-once)
#pragma unroll
    for (int mt = 0; mt < 2; ++mt) {
#pragma unroll
        for (int r = 0; r < 4; ++r) {
            int row = wm * 32 + mt * 16 + quad * 4 + r;
            float* po = Ob + (size_t)row * H_ + wn * 64 + lane15;
#pragma unroll
            for (int nt = 0; nt < 4; ++nt)
                __builtin_nontemporal_store(acc[mt][nt][r], po + nt * 16);
        }
    }
}

extern "C" void kernel_launch(void* const* d_in, const int* in_sizes, int n_in,
                              void* d_out, int out_size, void* d_ws, size_t ws_size,
                              hipStream_t stream) {
    const float* x     = (const float*)d_in[0];   // [8][4096][256]
    const float* t     = (const float*)d_in[1];   // [8][1]
    const float* osc   = (const float*)d_in[2];   // [6][256][256]
    const float* phase = (const float*)d_in[3];   // [6][256]
    __hip_bfloat16* Wt = (__hip_bfloat16*)d_ws;   // ws poison is unconditional -> free
    float* out = (float*)d_out;
    (void)in_sizes; (void)n_in; (void)out_size; (void)ws_size;

    dim3 gw(16, 4, 8);                            // (h-slice, n-tile, b) = 512 blocks
    build_w<<<gw, 256, 0, stream>>>(osc, t, phase, Wt);

    dim3 gg(64, 8);                               // (mTile, b) = 512 blocks
    gemm<<<gg, 512, 0, stream>>>(x, Wt, out);
}